// Round 13
// baseline (95.200 us; speedup 1.0000x reference)
//
#include <hip/hip_runtime.h>
#include <math.h>

#define N_TOK 2048
#define NDIM 512
#define HEADS 8
#define TOPK 16
#define QCOLS 4096
#define LSC 4096.0f          // lo-part scale 2^12 (exact)
#define ILSC (1.0f/4096.0f)

typedef __attribute__((ext_vector_type(8))) _Float16 f16x8;
typedef __attribute__((ext_vector_type(4))) float f32x4;

__device__ __forceinline__ unsigned short f32_to_f16(float f) {
    _Float16 h = (_Float16)f;
    return __builtin_bit_cast(unsigned short, h);
}
__device__ __forceinline__ float f16_to_f32(unsigned short u) {
    return (float)__builtin_bit_cast(_Float16, u);
}
__device__ __forceinline__ void gl_lds16(const void* g, void* l) {
    __builtin_amdgcn_global_load_lds(
        (const __attribute__((address_space(1))) void*)g,
        (__attribute__((address_space(3))) void*)l, 16, 0, 0);
}

// ---------------- kP: fp32 -> fp16 hi + SCALED lo (lo*4096, keeps lo NORMAL fp16)
__device__ __forceinline__ void split_f4(const float* __restrict__ src,
                                         unsigned short* __restrict__ dh,
                                         unsigned short* __restrict__ dl,
                                         int i) {
    float4 v = reinterpret_cast<const float4*>(src)[i];
    float vv[4] = {v.x, v.y, v.z, v.w};
    ushort4 h, lo;
    unsigned short* hp = &h.x; unsigned short* lp = &lo.x;
    #pragma unroll
    for (int q = 0; q < 4; ++q) {
        unsigned short hh = f32_to_f16(vv[q]);
        hp[q] = hh;
        lp[q] = f32_to_f16((vv[q] - f16_to_f32(hh)) * LSC);
    }
    reinterpret_cast<ushort4*>(dh)[i] = h;
    reinterpret_cast<ushort4*>(dl)[i] = lo;
}

__global__ __launch_bounds__(256) void kP_split(const float* __restrict__ x,
                                                const float* __restrict__ Wq,
                                                const float* __restrict__ keys,
                                                const float* __restrict__ down,
                                                const float* __restrict__ up,
                                                unsigned short* __restrict__ xh,
                                                unsigned short* __restrict__ xl,
                                                unsigned short* __restrict__ Wqh,
                                                unsigned short* __restrict__ Wql,
                                                unsigned short* __restrict__ ksh,
                                                unsigned short* __restrict__ ksl,
                                                unsigned short* __restrict__ Mth,
                                                unsigned short* __restrict__ Mtl,
                                                unsigned short* __restrict__ upTh,
                                                unsigned short* __restrict__ upTl) {
    const int bid = blockIdx.x;
    const int tid = threadIdx.x;
    if (bid < 256) {                     // x: 262,144 f4
        #pragma unroll
        for (int t = 0; t < 4; ++t) split_f4(x, xh, xl, bid * 1024 + t * 256 + tid);
        return;
    }
    if (bid < 768) {                     // Wq: 524,288 f4
        const int b = bid - 256;
        #pragma unroll
        for (int t = 0; t < 4; ++t) split_f4(Wq, Wqh, Wql, b * 1024 + t * 256 + tid);
        return;
    }
    if (bid < 1024) {                    // keys: 262,144 f4
        const int b = bid - 768;
        #pragma unroll
        for (int t = 0; t < 4; ++t) split_f4(keys, ksh, ksl, b * 1024 + t * 256 + tid);
        return;
    }
    if (bid < 1280) {                    // down row e -> Mt row 4096+e
        const int e = bid - 1024;
        const int d0 = tid * 2;
        float2 v = *reinterpret_cast<const float2*>(&down[(size_t)e * NDIM + d0]);
        ushort2 h, lo;
        unsigned short h0 = f32_to_f16(v.x);
        unsigned short h1 = f32_to_f16(v.y);
        h.x = h0; h.y = h1;
        lo.x = f32_to_f16((v.x - f16_to_f32(h0)) * LSC);
        lo.y = f32_to_f16((v.y - f16_to_f32(h1)) * LSC);
        *reinterpret_cast<ushort2*>(&Mth[(size_t)(QCOLS + e) * NDIM + d0]) = h;
        *reinterpret_cast<ushort2*>(&Mtl[(size_t)(QCOLS + e) * NDIM + d0]) = lo;
        return;
    }
    // upT: up[e][d] -> upTh/upTl[d][e]   (64 blocks)
    const int b = bid - 1280;
    #pragma unroll
    for (int dd = 0; dd < 8; ++dd) {
        const int d = b * 8 + dd;
        const int e = tid;
        const float v = up[(size_t)e * NDIM + d];
        unsigned short hh = f32_to_f16(v);
        upTh[(size_t)d * 256 + e] = hh;
        upTl[(size_t)d * 256 + e] = f32_to_f16((v - f16_to_f32(hh)) * LSC);
    }
}

// ---------------- kQ: M = Wq_slice @ keys^T, split-accumulate (hi / scaled-lo)
__global__ __launch_bounds__(256) void kQ_m1(const unsigned short* __restrict__ Wqh,
                                             const unsigned short* __restrict__ Wql,
                                             const unsigned short* __restrict__ ksh,
                                             const unsigned short* __restrict__ ksl,
                                             unsigned short* __restrict__ Mth,
                                             unsigned short* __restrict__ Mtl) {
    __shared__ __align__(16) char lds[36864];   // A 4KB + B 32KB
    const int tid = threadIdx.x;
    const int w = tid >> 6, l = tid & 63;
    const int c0 = blockIdx.x * 32;
    const int ph = blockIdx.y;
    const int p = ph >> 3, h = ph & 7;
    const int off = p * 2048 + h * 256;
    f32x4 acch[2][4] = {};
    f32x4 accl[2][4] = {};

    for (int s = 0; s < 8; ++s) {
        const int kk = s * 32;
        __syncthreads();
        {   // A: 32 rows x 128B = 4KB
            const int q = w * 1024 + l * 16;
            const int r = q >> 7;
            const int bsw = (q & 127) ^ ((r & 7) << 4);
            const unsigned short* src = (bsw < 64)
                ? Wqh + (size_t)(c0 + r) * QCOLS + off + kk + (bsw >> 1)
                : Wql + (size_t)(c0 + r) * QCOLS + off + kk + ((bsw - 64) >> 1);
            gl_lds16(src, lds + w * 1024);
        }
        #pragma unroll
        for (int t = 0; t < 8; ++t) {   // B: 256 rows x 128B = 32KB
            const int q = w * 8192 + t * 1024 + l * 16;
            const int r = q >> 7;
            const int bsw = (q & 127) ^ ((r & 7) << 4);
            const unsigned short* src = (bsw < 64)
                ? ksh + ((size_t)(h * 256 + r) * 2 + p) * 256 + kk + (bsw >> 1)
                : ksl + ((size_t)(h * 256 + r) * 2 + p) * 256 + kk + ((bsw - 64) >> 1);
            gl_lds16(src, lds + 4096 + w * 8192 + t * 1024);
        }
        __syncthreads();
        const int bq = (l >> 4) * 16;
        f16x8 ah[2], al[2];
        #pragma unroll
        for (int mi = 0; mi < 2; ++mi) {
            const int ra = mi * 16 + (l & 15);
            const int swz = (ra & 7) << 4;
            ah[mi] = *(const f16x8*)(lds + ra * 128 + (bq ^ swz));
            al[mi] = *(const f16x8*)(lds + ra * 128 + ((bq + 64) ^ swz));
        }
        __builtin_amdgcn_s_setprio(1);
        #pragma unroll
        for (int nj = 0; nj < 4; ++nj) {
            const int rb = w * 64 + nj * 16 + (l & 15);
            const int swz = (rb & 7) << 4;
            f16x8 bh = *(const f16x8*)(lds + 4096 + rb * 128 + (bq ^ swz));
            f16x8 bl = *(const f16x8*)(lds + 4096 + rb * 128 + ((bq + 64) ^ swz));
            #pragma unroll
            for (int mi = 0; mi < 2; ++mi) {
                acch[mi][nj] = __builtin_amdgcn_mfma_f32_16x16x32_f16(ah[mi], bh, acch[mi][nj], 0, 0, 0);
                accl[mi][nj] = __builtin_amdgcn_mfma_f32_16x16x32_f16(ah[mi], bl, accl[mi][nj], 0, 0, 0);
                accl[mi][nj] = __builtin_amdgcn_mfma_f32_16x16x32_f16(al[mi], bh, accl[mi][nj], 0, 0, 0);
            }
        }
        __builtin_amdgcn_s_setprio(0);
    }
    #pragma unroll
    for (int mi = 0; mi < 2; ++mi)
        #pragma unroll
        for (int nj = 0; nj < 4; ++nj) {
            const int k = w * 64 + nj * 16 + (l & 15);
            const int cb = c0 + mi * 16 + (l >> 4) * 4;
            ushort4 h4, l4;
            unsigned short* hp = &h4.x; unsigned short* lp = &l4.x;
            #pragma unroll
            for (int r = 0; r < 4; ++r) {
                const float v = fmaf(accl[mi][nj][r], ILSC, acch[mi][nj][r]);
                unsigned short hh = f32_to_f16(v);
                hp[r] = hh;
                lp[r] = f32_to_f16((v - f16_to_f32(hh)) * LSC);
            }
            *reinterpret_cast<ushort4*>(&Mth[(size_t)(off + k) * NDIM + cb]) = h4;
            *reinterpret_cast<ushort4*>(&Mtl[(size_t)(off + k) * NDIM + cb]) = l4;
        }
}

// ---------------- KF: fused sim GEMM + phase-1 half-group top-16.
// BM=128, BN=128, BK=32, dbuf; split-accumulate hi / scaled-lo.
#define BM 128
#define BN 128
#define BK 32
#define KFBUF 32768
__global__ __launch_bounds__(256, 2) void kF_gemm(const unsigned short* __restrict__ xh,
                                                  const unsigned short* __restrict__ xl,
                                                  const unsigned short* __restrict__ Mth,
                                                  const unsigned short* __restrict__ Mtl,
                                                  float* __restrict__ T,
                                                  float* __restrict__ D) {
    __shared__ __align__(16) char lds[2 * KFBUF];   // 64 KB
    const int tid = threadIdx.x;
    const int w = tid >> 6, l = tid & 63;
    const int row0 = blockIdx.x * BM;
    const int by = blockIdx.y;
    const int colbase = by * 128;
    f32x4 acch[8][2] = {};
    f32x4 accl[8][2] = {};

    auto stage = [&](int buf, int s) {
        const int kk = s * BK;
        char* base = lds + buf * KFBUF;
        #pragma unroll
        for (int t = 0; t < 4; ++t) {                 // A: 128 rows x 128B = 16KB
            const int q = w * 4096 + t * 1024 + l * 16;
            const int r = q >> 7;
            const int bsw = (q & 127) ^ ((r & 7) << 4);
            const unsigned short* src = (bsw < 64)
                ? xh + (size_t)(row0 + r) * NDIM + kk + (bsw >> 1)
                : xl + (size_t)(row0 + r) * NDIM + kk + ((bsw - 64) >> 1);
            gl_lds16(src, base + w * 4096 + t * 1024);
        }
        #pragma unroll
        for (int t = 0; t < 4; ++t) {                 // B: 128 rows x 128B = 16KB
            const int q = w * 4096 + t * 1024 + l * 16;
            const int r = q >> 7;
            const int bsw = (q & 127) ^ ((r & 7) << 4);
            const unsigned short* src = (bsw < 64)
                ? Mth + (size_t)(colbase + r) * NDIM + kk + (bsw >> 1)
                : Mtl + (size_t)(colbase + r) * NDIM + kk + ((bsw - 64) >> 1);
            gl_lds16(src, base + 16384 + w * 4096 + t * 1024);
        }
    };

    stage(0, 0);
    __syncthreads();
    for (int s = 0; s < 16; ++s) {
        if (s + 1 < 16) stage((s + 1) & 1, s + 1);
        const char* base = lds + (s & 1) * KFBUF;
        const int bq = (l >> 4) * 16;
        f16x8 bh[2], bl[2];
        #pragma unroll
        for (int nj = 0; nj < 2; ++nj) {
            const int rb = w * 32 + nj * 16 + (l & 15);
            const int swz = (rb & 7) << 4;
            bh[nj] = *(const f16x8*)(base + 16384 + rb * 128 + (bq ^ swz));
            bl[nj] = *(const f16x8*)(base + 16384 + rb * 128 + ((bq + 64) ^ swz));
        }
        __builtin_amdgcn_s_setprio(1);
        #pragma unroll
        for (int mi = 0; mi < 8; ++mi) {
            const int ra = mi * 16 + (l & 15);
            const int swz = (ra & 7) << 4;
            f16x8 ah = *(const f16x8*)(base + ra * 128 + (bq ^ swz));
            f16x8 al = *(const f16x8*)(base + ra * 128 + ((bq + 64) ^ swz));
            #pragma unroll
            for (int nj = 0; nj < 2; ++nj) {
                acch[mi][nj] = __builtin_amdgcn_mfma_f32_16x16x32_f16(ah, bh[nj], acch[mi][nj], 0, 0, 0);
                accl[mi][nj] = __builtin_amdgcn_mfma_f32_16x16x32_f16(ah, bl[nj], accl[mi][nj], 0, 0, 0);
                accl[mi][nj] = __builtin_amdgcn_mfma_f32_16x16x32_f16(al, bh[nj], accl[mi][nj], 0, 0, 0);
            }
        }
        __builtin_amdgcn_s_setprio(0);
        __syncthreads();
    }

    if (by >= 32) {     // D half-block: direct store (combine hi + lo/4096)
        #pragma unroll
        for (int mi = 0; mi < 8; ++mi)
            #pragma unroll
            for (int nj = 0; nj < 2; ++nj)
                #pragma unroll
                for (int r = 0; r < 4; ++r) {
                    const int row = row0 + mi * 16 + (l >> 4) * 4 + r;
                    const int col = (by - 32) * 128 + w * 32 + nj * 16 + (l & 15);
                    D[(size_t)row * 256 + col] = fmaf(accl[mi][nj][r], ILSC, acch[mi][nj][r]);
                }
        return;
    }

    // epilogue: 4 chunks of 32 rows; Cl[32][136]
    float* Cl = (float*)lds;
    const int grp8 = tid >> 3;
    const int lam8 = tid & 7;
    for (int c = 0; c < 4; ++c) {
        #pragma unroll
        for (int mm = 0; mm < 2; ++mm) {
            const int mi = c * 2 + mm;
            #pragma unroll
            for (int nj = 0; nj < 2; ++nj)
                #pragma unroll
                for (int r = 0; r < 4; ++r)
                    Cl[(mm * 16 + (l >> 4) * 4 + r) * 136 + w * 32 + nj * 16 + (l & 15)] =
                        fmaf(accl[mi][nj][r], ILSC, acch[mi][nj][r]);
        }
        __syncthreads();
        float v[16];
        #pragma unroll
        for (int j = 0; j < 16; ++j) v[j] = Cl[grp8 * 136 + lam8 + 8 * j];
        #pragma unroll
        for (int k = 2; k <= 16; k <<= 1)
            #pragma unroll
            for (int j = k >> 1; j > 0; j >>= 1)
                #pragma unroll
                for (int i = 0; i < 16; ++i) {
                    const int l2 = i ^ j;
                    if (l2 > i) {
                        const bool asc = ((i & k) == 0);
                        const float lo = fminf(v[i], v[l2]), hi = fmaxf(v[i], v[l2]);
                        v[i] = asc ? lo : hi;
                        v[l2] = asc ? hi : lo;
                    }
                }
        #pragma unroll
        for (int lvl = 1; lvl <= 4; lvl <<= 1) {
            float m[16];
            #pragma unroll
            for (int q = 0; q < 16; ++q)
                m[q] = fmaxf(v[q], __shfl_xor(v[15 - q], lvl));
            #pragma unroll
            for (int j = 8; j > 0; j >>= 1)
                #pragma unroll
                for (int i = 0; i < 16; ++i) {
                    const int l2 = i ^ j;
                    if (l2 > i) {
                        const float lo = fminf(m[i], m[l2]), hi = fmaxf(m[i], m[l2]);
                        m[i] = lo; m[l2] = hi;
                    }
                }
            #pragma unroll
            for (int q = 0; q < 16; ++q) v[q] = m[q];
        }
        const int n = row0 + c * 32 + grp8;
        T[((size_t)n * 32 + by) * 16 + 2 * lam8]     = v[15 - 2 * lam8];
        T[((size_t)n * 32 + by) * 16 + 2 * lam8 + 1] = v[14 - 2 * lam8];
        __syncthreads();
    }
}

// ---------------- KC: merge half-lists -> 50 candidates -> top-16 -> softmax*gelu(D)
__device__ const unsigned short CAND_TBL[32] = {
    0x0100, 0x0302, 0x0504, 0x0706, 0x0908, 0x0B0A, 0x0D0C, 0x0F0E,
    0x1110, 0x1312, 0x1514, 0x1716,
    0x2120, 0x2322, 0x3024, 0x3231, 0x4033, 0x4241,
    0x5150, 0x6160, 0x7170,
    0x9080, 0xB0A0, 0xD0C0, 0xF0E0,
    0xFFFF, 0xFFFF, 0xFFFF, 0xFFFF, 0xFFFF, 0xFFFF, 0xFFFF
};

__device__ __forceinline__ float sel16(const float a[16], int i) {
    float b0 = (i & 1) ? a[1] : a[0];
    float b1 = (i & 1) ? a[3] : a[2];
    float b2 = (i & 1) ? a[5] : a[4];
    float b3 = (i & 1) ? a[7] : a[6];
    float b4 = (i & 1) ? a[9] : a[8];
    float b5 = (i & 1) ? a[11] : a[10];
    float b6 = (i & 1) ? a[13] : a[12];
    float b7 = (i & 1) ? a[15] : a[14];
    float c0 = (i & 2) ? b1 : b0;
    float c1 = (i & 2) ? b3 : b2;
    float c2 = (i & 2) ? b5 : b4;
    float c3 = (i & 2) ? b7 : b6;
    float d0 = (i & 4) ? c1 : c0;
    float d1 = (i & 4) ? c3 : c2;
    return (i & 8) ? d1 : d0;
}

__device__ __forceinline__ void merge_desc16(const float* __restrict__ a,
                                             const float* __restrict__ b,
                                             float out_desc[16]) {
    float m[16];
    #pragma unroll
    for (int q = 0; q < 16; ++q) m[q] = fmaxf(a[q], b[15 - q]);
    #pragma unroll
    for (int k = 2; k <= 16; k <<= 1)
        #pragma unroll
        for (int j = k >> 1; j > 0; j >>= 1)
            #pragma unroll
            for (int i = 0; i < 16; ++i) {
                const int l2 = i ^ j;
                if (l2 > i) {
                    const bool asc = ((i & k) == 0);
                    const float lo = fminf(m[i], m[l2]), hi = fmaxf(m[i], m[l2]);
                    m[i] = asc ? lo : hi;
                    m[l2] = asc ? hi : lo;
                }
            }
    #pragma unroll
    for (int q = 0; q < 16; ++q) out_desc[q] = m[15 - q];
}

__global__ __launch_bounds__(256) void kC_combine(const float* __restrict__ T,
                                                  const float* __restrict__ D,
                                                  unsigned short* __restrict__ Wh,
                                                  unsigned short* __restrict__ Wl) {
    __shared__ unsigned long long ckey[8][50];
    __shared__ float winval[8][16];
    __shared__ int winflat[8][16];
    __shared__ int Wrow[256];

    const int tid = threadIdx.x;
    const int n = blockIdx.x;
    const int h = tid >> 5;
    const int lam = tid & 15;

    Wrow[tid] = 0;

    float a0[16], a1[16], b0v[16], b1v[16];
    const float* t00 = &T[((size_t)n * 32 + 2 * h) * 16];
    const float* t01 = &T[((size_t)n * 32 + 2 * h + 1) * 16];
    const float* t10 = &T[((size_t)n * 32 + 16 + 2 * h) * 16];
    const float* t11 = &T[((size_t)n * 32 + 17 + 2 * h) * 16];
    #pragma unroll
    for (int q = 0; q < 16; ++q) {
        a0[q] = t00[q]; a1[q] = t01[q];
        b0v[q] = t10[q]; b1v[q] = t11[q];
    }
    float sxd[16], syd[16];
    merge_desc16(a0, a1, sxd);
    merge_desc16(b0v, b1v, syd);

    const int lc = tid & 31;
    const unsigned int cw = CAND_TBL[lc];
    unsigned long long mykey[2]; float myval[2]; int myflat[2]; int myrank[2] = {0, 0};
    #pragma unroll
    for (int u = 0; u < 2; ++u) {
        const int fl = (cw >> (8 * u)) & 0xFF;
        const float sv = sel16(sxd, fl >> 4) + sel16(syd, fl & 15);
        const unsigned int uv = __float_as_uint(sv);
        const unsigned int mo = (uv & 0x80000000u) ? ~uv : (uv | 0x80000000u);
        mykey[u] = ((unsigned long long)mo << 8) | (unsigned long long)(255 - fl);
        myval[u] = sv; myflat[u] = fl;
        const int slot = lc * 2 + u;
        if (slot < 50) ckey[h][slot] = mykey[u];
    }
    __syncthreads();
    for (int kk = 0; kk < 50; ++kk) {
        const unsigned long long ok = ckey[h][kk];
        myrank[0] += (ok > mykey[0]) ? 1 : 0;
        myrank[1] += (ok > mykey[1]) ? 1 : 0;
    }
    #pragma unroll
    for (int u = 0; u < 2; ++u)
        if (myrank[u] < 16) { winval[h][myrank[u]] = myval[u]; winflat[h][myrank[u]] = myflat[u]; }
    __syncthreads();

    if (!(tid & 16)) {
        const float sc = winval[h][lam];
        const float m0 = winval[h][0];
        float e = expf(sc - m0);
        float esum = e;
        #pragma unroll
        for (int off = 1; off < 16; off <<= 1) esum += __shfl_xor(esum, off);
        const int fl = winflat[h][lam];
        const float hv = D[(size_t)n * 256 + fl];
        const float gg = 0.5f * hv * (1.0f + erff(hv * 0.70710678118654752f));
        const float wv = (e / esum) * gg;
        atomicAdd(&Wrow[fl], __float2int_rn(wv * 4194304.0f));
    }
    __syncthreads();
    const float wfin = (float)Wrow[tid] * (1.0f / 4194304.0f);
    const unsigned short hh = f32_to_f16(wfin);
    Wh[(size_t)n * 256 + tid] = hh;
    Wl[(size_t)n * 256 + tid] = f32_to_f16((wfin - f16_to_f32(hh)) * LSC);
}

// ---------------- k5: out = W @ up256, split-accumulate hi / scaled-lo
__global__ __launch_bounds__(256) void k5_mfma(const unsigned short* __restrict__ Wh,
                                               const unsigned short* __restrict__ Wl,
                                               const unsigned short* __restrict__ upTh,
                                               const unsigned short* __restrict__ upTl,
                                               float* __restrict__ out) {
    __shared__ __align__(16) char lds[20480];   // A 4KB + B 16KB
    const int tid = threadIdx.x;
    const int w = tid >> 6, l = tid & 63;
    const int n0 = blockIdx.x * 32;
    const int d0 = blockIdx.y * 128;
    f32x4 acch[2][2] = {};
    f32x4 accl[2][2] = {};

    for (int s = 0; s < 8; ++s) {
        const int kk = s * 32;
        __syncthreads();
        {   // A: W rows 32 x 128B = 4KB
            const int q = w * 1024 + l * 16;
            const int r = q >> 7;
            const int bsw = (q & 127) ^ ((r & 7) << 4);
            const unsigned short* src = (bsw < 64)
                ? Wh + (size_t)(n0 + r) * 256 + kk + (bsw >> 1)
                : Wl + (size_t)(n0 + r) * 256 + kk + ((bsw - 64) >> 1);
            gl_lds16(src, lds + w * 1024);
        }
        #pragma unroll
        for (int t = 0; t < 4; ++t) {   // B: upT rows 128 x 128B = 16KB
            const int q = w * 4096 + t * 1024 + l * 16;
            const int r = q >> 7;
            const int bsw = (q & 127) ^ ((r & 7) << 4);
            const unsigned short* src = (bsw < 64)
                ? upTh + (size_t)(d0 + r) * 256 + kk + (bsw >> 1)
                : upTl + (size_t)(d0 + r) * 256 + kk + ((bsw - 64) >> 1);
            gl_lds16(src, lds + 4096 + w * 4096 + t * 1024);
        }
        __syncthreads();
        const int bq = (l >> 4) * 16;
        f16x8 ah[2], al[2];
        #pragma unroll
        for (int mi = 0; mi < 2; ++mi) {
            const int ra = mi * 16 + (l & 15);
            const int swz = (ra & 7) << 4;
            ah[mi] = *(const f16x8*)(lds + ra * 128 + (bq ^ swz));
            al[mi] = *(const f16x8*)(lds + ra * 128 + ((bq + 64) ^ swz));
        }
        #pragma unroll
        for (int nj = 0; nj < 2; ++nj) {
            const int rb = w * 32 + nj * 16 + (l & 15);
            const int swz = (rb & 7) << 4;
            f16x8 bh = *(const f16x8*)(lds + 4096 + rb * 128 + (bq ^ swz));
            f16x8 bl = *(const f16x8*)(lds + 4096 + rb * 128 + ((bq + 64) ^ swz));
            #pragma unroll
            for (int mi = 0; mi < 2; ++mi) {
                acch[mi][nj] = __builtin_amdgcn_mfma_f32_16x16x32_f16(ah[mi], bh, acch[mi][nj], 0, 0, 0);
                accl[mi][nj] = __builtin_amdgcn_mfma_f32_16x16x32_f16(ah[mi], bl, accl[mi][nj], 0, 0, 0);
                accl[mi][nj] = __builtin_amdgcn_mfma_f32_16x16x32_f16(al[mi], bh, accl[mi][nj], 0, 0, 0);
            }
        }
    }
    #pragma unroll
    for (int mi = 0; mi < 2; ++mi)
        #pragma unroll
        for (int nj = 0; nj < 2; ++nj)
            #pragma unroll
            for (int r = 0; r < 4; ++r) {
                const int row = n0 + mi * 16 + (l >> 4) * 4 + r;
                const int col = d0 + w * 32 + nj * 16 + (l & 15);
                out[(size_t)row * NDIM + col] = fmaf(accl[mi][nj][r], ILSC, acch[mi][nj][r]);
            }
}

extern "C" void kernel_launch(void* const* d_in, const int* in_sizes, int n_in,
                              void* d_out, int out_size, void* d_ws, size_t ws_size,
                              hipStream_t stream) {
    const float* x    = (const float*)d_in[0];
    const float* Wq   = (const float*)d_in[1];
    const float* keys = (const float*)d_in[2];
    const float* down = (const float*)d_in[3];
    const float* up   = (const float*)d_in[4];
    float* out = (float*)d_out;

    char* ws = (char*)d_ws;
    unsigned short* Mth  = (unsigned short*)(ws);                  // 4,456,448 B
    unsigned short* Mtl  = (unsigned short*)(ws + 4456448);        // 4,456,448 B
    unsigned short* xh   = (unsigned short*)(ws + 8912896);        // 2,097,152 B
    unsigned short* xl   = (unsigned short*)(ws + 11010048);       // 2,097,152 B
    unsigned short* Wqh  = (unsigned short*)(ws + 13107200);       // 4,194,304 B
    unsigned short* Wql  = (unsigned short*)(ws + 17301504);       // 4,194,304 B
    unsigned short* ksh  = (unsigned short*)(ws + 21495808);       // 2,097,152 B
    unsigned short* ksl  = (unsigned short*)(ws + 23592960);       // 2,097,152 B
    unsigned short* upTh = (unsigned short*)(ws + 25690112);       //   262,144 B
    unsigned short* upTl = (unsigned short*)(ws + 25952256);       //   262,144 B
    float* T             = (float*)(ws + 26214400);                // 4,194,304 B
    float* D             = (float*)(ws + 30408704);                // 2,097,152 B
    unsigned short* Wh   = (unsigned short*)(ws + 32505856);       // 1,048,576 B
    unsigned short* Wl   = (unsigned short*)(ws + 33554432);       // 1,048,576 B

    kP_split<<<1344, 256, 0, stream>>>(x, Wq, keys, down, up,
                                       xh, xl, Wqh, Wql, ksh, ksl, Mth, Mtl, upTh, upTl);
    kQ_m1<<<dim3(16, 16), 256, 0, stream>>>(Wqh, Wql, ksh, ksl, Mth, Mtl);
    kF_gemm<<<dim3(16, 34), 256, 0, stream>>>(xh, xl, Mth, Mtl, T, D);
    kC_combine<<<2048, 256, 0, stream>>>(T, D, Wh, Wl);
    k5_mfma<<<dim3(64, 4), 256, 0, stream>>>(Wh, Wl, upTh, upTl, out);
}